// Round 4
// baseline (1866.586 us; speedup 1.0000x reference)
//
#include <hip/hip_runtime.h>
#include <hip/hip_bf16.h>

#define NCN 300000
#define NAN_ 100000
#define DIM 128
#define NE 2000000
#define NL 1000000
#define NBA 1563          // ceil(NAN_/64)
#define NBC 4688          // ceil(NCN/64)
#define ECH 8192          // edges per binning block
#define NCHUNK ((NE + ECH - 1) / ECH)

typedef __attribute__((ext_vector_type(8))) short bf16x8;
typedef __attribute__((ext_vector_type(4))) float f32x4;
typedef __attribute__((ext_vector_type(8))) unsigned short u16x8;
typedef __attribute__((ext_vector_type(4))) unsigned short u16x4;

static __device__ __forceinline__ unsigned short f2bf(float x){
  union { float f; unsigned u; } v; v.f = x;
  unsigned r = (v.u + 0x7FFFu + ((v.u >> 16) & 1u)) >> 16;
  return (unsigned short)r;
}
static __device__ __forceinline__ float bf2f(unsigned short h){
  union { unsigned u; float f; } v; v.u = ((unsigned)h) << 16; return v.f;
}

// ---------------- fp32 -> bf16 cast ----------------
__global__ void k_cast(const float* __restrict__ x, unsigned short* __restrict__ y, int n4){
  int i = blockIdx.x * blockDim.x + threadIdx.x;
  if (i < n4){
    float4 v = ((const float4*)x)[i];
    u16x4 h;
    h[0] = f2bf(v.x); h[1] = f2bf(v.y); h[2] = f2bf(v.z); h[3] = f2bf(v.w);
    ((u16x4*)y)[i] = h;
  }
}

// ---------- pass 0: per-block LDS histogram of 64-wide dst buckets, both dirs ----------
__global__ void k_bcnt(const int* __restrict__ src, const int* __restrict__ dst,
                       int* cntA, int* cntC){
  __shared__ int h[NBA + NBC];
  int t = threadIdx.x;
  for (int i = t; i < NBA + NBC; i += 256) h[i] = 0;
  __syncthreads();
  int e0 = blockIdx.x * ECH;
  int e1 = e0 + ECH < NE ? e0 + ECH : NE;
  for (int e = e0 + t; e < e1; e += 256){
    int s = src[e], d = dst[e];
    atomicAdd(&h[d >> 6], 1);
    atomicAdd(&h[NBA + (s >> 6)], 1);
  }
  __syncthreads();
  for (int i = t; i < NBA + NBC; i += 256){
    int c = h[i];
    if (c > 0){
      if (i < NBA) atomicAdd(&cntA[i], c);
      else         atomicAdd(&cntC[i - NBA], c);
    }
  }
}

// ---------- scan bucket counts (block 0: A, block 1: C); writes base (excl) + cur copy ----
__global__ void k_scan2(const int* cA, int* bA, int* uA,
                        const int* cC, int* bC, int* uC){
  const int* c; int* bs; int* cu; int n;
  if (blockIdx.x == 0){ c = cA; bs = bA; cu = uA; n = NBA; }
  else                { c = cC; bs = bC; cu = uC; n = NBC; }
  int t = threadIdx.x;
  int per = (n + 255) / 256;          // <= 19
  int b0 = t * per;
  int vals[19];
  int s = 0;
  for (int i = 0; i < per; i++){
    int idx = b0 + i;
    int x = (idx < n) ? c[idx] : 0;
    vals[i] = s; s += x;
  }
  int lane = t & 63, w = t >> 6;
  int inc = s;
  #pragma unroll
  for (int o = 1; o < 64; o <<= 1){ int u = __shfl_up(inc, o); if (lane >= o) inc += u; }
  __shared__ int ws[4];
  if (lane == 63) ws[w] = inc;
  __syncthreads();
  int woff = 0;
  for (int j = 0; j < w; j++) woff += ws[j];
  int ex = woff + inc - s;
  for (int i = 0; i < per; i++){
    int idx = b0 + i;
    if (idx < n){ int v = ex + vals[i]; bs[idx] = v; cu[idx] = v; }
  }
  if (t == 255) bs[n] = ex + s;       // == NE
}

// ---------- pass 1: partition edges into packed (dstlow<<26|src) per bucket ----------
__global__ void k_bin(const int* __restrict__ src, const int* __restrict__ dst,
                      int* curA, int* curC, unsigned* binA, unsigned* binC){
  __shared__ int h[NBA + NBC];
  int t = threadIdx.x;
  for (int i = t; i < NBA + NBC; i += 256) h[i] = 0;
  __syncthreads();
  int e0 = blockIdx.x * ECH;
  int e1 = e0 + ECH < NE ? e0 + ECH : NE;
  for (int e = e0 + t; e < e1; e += 256){
    int s = src[e], d = dst[e];
    atomicAdd(&h[d >> 6], 1);
    atomicAdd(&h[NBA + (s >> 6)], 1);
  }
  __syncthreads();
  for (int i = t; i < NBA + NBC; i += 256){
    int c = h[i];
    if (c > 0){
      int base = (i < NBA) ? atomicAdd(&curA[i], c) : atomicAdd(&curC[i - NBA], c);
      h[i] = base;
    }
  }
  __syncthreads();
  for (int e = e0 + t; e < e1; e += 256){
    int s = src[e], d = dst[e];
    int pa = atomicAdd(&h[d >> 6], 1);
    binA[pa] = ((unsigned)(d & 63) << 26) | (unsigned)s;
    int pc = atomicAdd(&h[NBA + (s >> 6)], 1);
    binC[pc] = ((unsigned)(s & 63) << 26) | (unsigned)d;
  }
}

// ---------- pass 2: per-bucket CSR finalize — emits rp and contiguous col ----------
__global__ void k_csr(const unsigned* __restrict__ bin, const int* __restrict__ base,
                      int* __restrict__ rp, int* __restrict__ col, int ndst, int nb){
  int b = blockIdx.x;
  int beg = base[b], end = base[b + 1];
  __shared__ int deg[64], cur[64];
  int t = threadIdx.x;
  if (t < 64) deg[t] = 0;
  __syncthreads();
  for (int i = beg + t; i < end; i += 256){
    unsigned p = bin[i];
    atomicAdd(&deg[p >> 26], 1);
  }
  __syncthreads();
  if (t < 64){
    int v = deg[t];
    int inc = v;
    #pragma unroll
    for (int o = 1; o < 64; o <<= 1){ int u = __shfl_up(inc, o); if (t >= o) inc += u; }
    int ex = beg + inc - v;
    cur[t] = ex;
    int d0 = b << 6;
    if (d0 + t < ndst) rp[d0 + t] = ex;
    if (b == nb - 1 && t == 0) rp[ndst] = base[nb];
  }
  __syncthreads();
  for (int i = beg + t; i < end; i += 256){
    unsigned p = bin[i];
    int pos = atomicAdd(&cur[p >> 26], 1);
    col[pos] = (int)(p & 0x03FFFFFFu);
  }
}

// ---- fused SAGE GEMM: out[Mx128] = meanCSR(gfeat)@WA (+ B@WB) + bias, opt relu/BN ----
// If rp!=null, phase-0 A-tile is gather-mean of gfeat over CSR (dst rows of this tile
// are a contiguous col[] range). Else phase-0 stages dense rows of A.
// WtA/WtB bf16 TRANSPOSED [n][k].
__global__ __launch_bounds__(256) void k_gemm(
    const unsigned short* __restrict__ A,
    const int* __restrict__ rp, const int* __restrict__ col,
    const unsigned short* __restrict__ gfeat,
    const unsigned short* __restrict__ WtA,
    const unsigned short* __restrict__ B, const unsigned short* __restrict__ WtB,
    const float* __restrict__ bias, unsigned short* out, int M, int doRelu,
    float* gsum, float* gsq)
{
  __shared__ unsigned short lA[128 * 128];   // 32 KB, xor-swizzled 16B chunks
  __shared__ unsigned short lW[128 * 128];   // 32 KB
  int t = threadIdx.x;
  int lane = t & 63, wv = t >> 6;
  int row0 = blockIdx.x * 128;
  int m = lane & 15, kq = lane >> 4;

  f32x4 acc[2][8];
  #pragma unroll
  for (int i = 0; i < 2; i++)
    #pragma unroll
    for (int j = 0; j < 8; j++) acc[i][j] = (f32x4){0.f, 0.f, 0.f, 0.f};

  for (int pass = 0; pass < 2; ++pass){
    const unsigned short* wt;
    if (pass == 0) wt = WtA;
    else {
      if (!B) break;
      __syncthreads();                 // protect LDS until pass-0 MFMA done
      wt = WtB;
    }
    // stage transposed weight swizzled (issue loads first)
    #pragma unroll
    for (int i = 0; i < 8; i++){
      int id = t + 256 * i;
      int n = id >> 4, cc = id & 15;
      u16x8 w = *(const u16x8*)(wt + n * 128 + cc * 8);
      int pc = cc ^ (n & 15);
      *(u16x8*)&lW[n * 128 + pc * 8] = w;
    }
    if (pass == 1 || rp == nullptr){
      const unsigned short* srcp = (pass == 0) ? A : B;
      #pragma unroll
      for (int i = 0; i < 8; i++){
        int id = t + 256 * i;
        int r = id >> 4, c = id & 15;
        int gr = row0 + r;
        u16x8 v = {0,0,0,0,0,0,0,0};
        if (gr < M) v = *(const u16x8*)(srcp + (size_t)gr * DIM + c * 8);
        int pc = c ^ (r & 15);
        *(u16x8*)&lA[r * 128 + pc * 8] = v;
      }
    } else {
      // gather-mean phase: wave wv handles local rows wv+4i; 4 edge-subgroups x unroll 2
      int g  = lane >> 4;        // 0..3
      int cl = lane & 15;        // 8-channel chunk
      for (int i = 0; i < 32; i++){
        int r = wv + 4 * i;
        int gr = row0 + r;
        float a0[8] = {0,0,0,0,0,0,0,0}, a1[8] = {0,0,0,0,0,0,0,0};
        int dg = 0;
        if (gr < M){
          int beg = rp[gr], end = rp[gr + 1];
          dg = end - beg;
          int j = beg + g;
          for (; j + 4 < end; j += 8){
            int s0 = col[j], s1 = col[j + 4];
            u16x8 v0 = *(const u16x8*)(gfeat + (size_t)s0 * DIM + cl * 8);
            u16x8 v1 = *(const u16x8*)(gfeat + (size_t)s1 * DIM + cl * 8);
            #pragma unroll
            for (int k = 0; k < 8; k++){ a0[k] += bf2f(v0[k]); a1[k] += bf2f(v1[k]); }
          }
          if (j < end){
            int s0 = col[j];
            u16x8 v0 = *(const u16x8*)(gfeat + (size_t)s0 * DIM + cl * 8);
            #pragma unroll
            for (int k = 0; k < 8; k++) a0[k] += bf2f(v0[k]);
          }
          #pragma unroll
          for (int k = 0; k < 8; k++){
            float a = a0[k] + a1[k];
            a += __shfl_xor(a, 16);
            a += __shfl_xor(a, 32);
            a0[k] = a;
          }
        }
        if (g == 0){
          float inv = 1.0f / (float)(dg > 1 ? dg : 1);
          u16x8 rv;
          #pragma unroll
          for (int k = 0; k < 8; k++) rv[k] = f2bf(a0[k] * inv);
          *(u16x8*)&lA[r * 128 + (cl ^ (r & 15)) * 8] = rv;
        }
      }
    }
    __syncthreads();
    #pragma unroll
    for (int kc = 0; kc < 4; kc++){
      int cA = kc * 4 + kq;
      int r0 = wv * 32 + m;
      int r1 = r0 + 16;
      bf16x8 a0 = *(const bf16x8*)&lA[r0 * 128 + (cA ^ m) * 8];
      bf16x8 a1 = *(const bf16x8*)&lA[r1 * 128 + (cA ^ m) * 8];
      #pragma unroll
      for (int ct = 0; ct < 8; ct++){
        int n = ct * 16 + m;
        bf16x8 bfrag = *(const bf16x8*)&lW[n * 128 + (cA ^ m) * 8];
        acc[0][ct] = __builtin_amdgcn_mfma_f32_16x16x32_bf16(a0, bfrag, acc[0][ct], 0, 0, 0);
        acc[1][ct] = __builtin_amdgcn_mfma_f32_16x16x32_bf16(a1, bfrag, acc[1][ct], 0, 0, 0);
      }
    }
  }
  // epilogue: D col = lane&15, row = (lane>>4)*4 + reg   [verified m89/m91]
  float* lsum = (float*)lA;   // LDS reuse after barrier
  float* lsq  = lsum + 128;
  if (gsum){
    __syncthreads();
    if (t < 128){ lsum[t] = 0.f; lsq[t] = 0.f; }
    __syncthreads();
  }
  #pragma unroll
  for (int ct = 0; ct < 8; ct++){
    int colv = ct * 16 + m;
    float bv = bias ? bias[colv] : 0.f;
    float ps = 0.f, pq = 0.f;
    #pragma unroll
    for (int rt = 0; rt < 2; rt++){
      int rbase = row0 + wv * 32 + rt * 16 + kq * 4;
      #pragma unroll
      for (int r = 0; r < 4; r++){
        int grow = rbase + r;
        if (grow < M){
          float vo = acc[rt][ct][r] + bv;
          if (doRelu) vo = fmaxf(vo, 0.f);
          out[(size_t)grow * DIM + colv] = f2bf(vo);
          ps += vo; pq += vo * vo;
        }
      }
    }
    if (gsum){
      atomicAdd(&lsum[colv], ps);
      atomicAdd(&lsq[colv], pq);
    }
  }
  if (gsum){
    __syncthreads();
    if (t < 128){
      atomicAdd(&gsum[t], lsum[t]);
      atomicAdd(&gsq[t],  lsq[t]);
    }
  }
}

// ---------------- weight transpose fp32 [k][n] -> bf16 [n][k], batched ----------------
struct WtArgs { const float* s[8]; };
__global__ void k_wtrans(WtArgs a, unsigned short* dstb){
  const float* W = a.s[blockIdx.x];
  unsigned short* Wt = dstb + blockIdx.x * 16384;
  int t = threadIdx.x;
  for (int i = 0; i < 64; i++){
    int id = t + 256 * i;
    int k = id >> 7, n = id & 127;
    Wt[n * 128 + k] = f2bf(W[id]);
  }
}

// bn finalize + fold BN into decoder weight halves; bfull = b_dec1 + t_c@Wc + t_a@Wa
__global__ void k_bnprep(const float* sums,   // [sum_a, sq_a, sum_c, sq_c] x128
                         const float* gc, const float* bc,
                         const float* ga, const float* ba,
                         const float* Wd1, const float* bd1,
                         unsigned short* Wpt_c, unsigned short* Wpt_a, float* bfull){
  int n = threadIdx.x;   // 128 threads
  __shared__ float sc[128], tc[128], sa[128], ta[128];
  {
    float mu = sums[256 + n] / (float)NCN;
    float var = sums[384 + n] / (float)NCN - mu * mu;
    float s = gc[n] * rsqrtf(var + 1e-5f);
    sc[n] = s; tc[n] = bc[n] - mu * s;
  }
  {
    float mu = sums[0 + n] / (float)NAN_;
    float var = sums[128 + n] / (float)NAN_ - mu * mu;
    float s = ga[n] * rsqrtf(var + 1e-5f);
    sa[n] = s; ta[n] = ba[n] - mu * s;
  }
  __syncthreads();
  float accv = bd1[n];
  for (int k = 0; k < 128; k++){
    float w1 = Wd1[k * DIM + n];
    float w2 = Wd1[(128 + k) * DIM + n];
    Wpt_c[n * 128 + k] = f2bf(sc[k] * w1);
    Wpt_a[n * 128 + k] = f2bf(sa[k] * w2);
    accv += tc[k] * w1 + ta[k] * w2;
  }
  bfull[n] = accv;
}

// ---------------- decoder: quarter-wave per edge, 2 edges in flight ----------------
__global__ void k_dec(const int* __restrict__ lc, const int* __restrict__ la,
                      const unsigned short* __restrict__ UC, const unsigned short* __restrict__ UA,
                      const float* __restrict__ bfull, const float* __restrict__ w2,
                      const float* __restrict__ b2, float* __restrict__ out, int Etot){
  int t  = blockIdx.x * blockDim.x + threadIdx.x;
  int sl = t & 15;
  int q  = t >> 4;
  int nq = (gridDim.x * blockDim.x) >> 4;
  float bb[8], ww[8];
  #pragma unroll
  for (int k = 0; k < 8; k++){ bb[k] = bfull[sl * 8 + k]; ww[k] = w2[sl * 8 + k]; }
  float b2v = b2[0];
  for (int e0 = q * 2; e0 < Etot; e0 += nq * 2){
    int e1 = e0 + 1;                  // Etot even -> always valid
    int ic0 = lc[e0], ia0 = la[e0];
    int ic1 = lc[e1], ia1 = la[e1];
    u16x8 uc0 = *(const u16x8*)(UC + (size_t)ic0 * DIM + sl * 8);
    u16x8 ua0 = *(const u16x8*)(UA + (size_t)ia0 * DIM + sl * 8);
    u16x8 uc1 = *(const u16x8*)(UC + (size_t)ic1 * DIM + sl * 8);
    u16x8 ua1 = *(const u16x8*)(UA + (size_t)ia1 * DIM + sl * 8);
    float d0 = 0.f, d1 = 0.f;
    #pragma unroll
    for (int k = 0; k < 8; k++){
      float x0 = fmaxf(bf2f(uc0[k]) + bf2f(ua0[k]) + bb[k], 0.f);
      float x1 = fmaxf(bf2f(uc1[k]) + bf2f(ua1[k]) + bb[k], 0.f);
      d0 += x0 * ww[k];
      d1 += x1 * ww[k];
    }
    #pragma unroll
    for (int o = 8; o; o >>= 1){ d0 += __shfl_xor(d0, o); d1 += __shfl_xor(d1, o); }
    if (sl == 0){ out[e0] = d0 + b2v; out[e1] = d1 + b2v; }
  }
}

extern "C" void kernel_launch(void* const* d_in, const int* in_sizes, int n_in,
                              void* d_out, int out_size, void* d_ws, size_t ws_size,
                              hipStream_t stream){
  const float* x_c  = (const float*)d_in[0];
  const float* x_a  = (const float*)d_in[1];
  const int* e_src  = (const int*)d_in[2];
  const int* e_dst  = (const int*)d_in[3];
  const int* l_c    = (const int*)d_in[4];
  const int* l_a    = (const int*)d_in[5];
  const float* Wm1ca = (const float*)d_in[6];
  const float* Ws1a  = (const float*)d_in[7];
  const float* b1a   = (const float*)d_in[8];
  const float* Wm1ac = (const float*)d_in[9];
  const float* Ws1c  = (const float*)d_in[10];
  const float* b1c   = (const float*)d_in[11];
  const float* Wm2ca = (const float*)d_in[12];
  const float* Ws2a  = (const float*)d_in[13];
  const float* b2a   = (const float*)d_in[14];
  const float* Wm2ac = (const float*)d_in[15];
  const float* Ws2c  = (const float*)d_in[16];
  const float* b2c   = (const float*)d_in[17];
  const float* bng_c = (const float*)d_in[18];
  const float* bnb_c = (const float*)d_in[19];
  const float* bng_a = (const float*)d_in[20];
  const float* bnb_a = (const float*)d_in[21];
  const float* Wd1   = (const float*)d_in[22];
  const float* bd1   = (const float*)d_in[23];
  const float* Wd2   = (const float*)d_in[24];
  const float* bd2   = (const float*)d_in[25];
  float* out = (float*)d_out;

  // workspace carve (~360 MB)
  char* p = (char*)d_ws;
  auto alloc = [&](size_t bytes) -> char* {
    char* r = p; p += (bytes + 255) & ~(size_t)255; return r;
  };
  int* cnt   = (int*)alloc((size_t)(NBA + NBC) * 4);
  int* cntA  = cnt;
  int* cntC  = cnt + NBA;
  int* baseA = (int*)alloc((size_t)(NBA + 1) * 4);
  int* baseC = (int*)alloc((size_t)(NBC + 1) * 4);
  int* curA  = (int*)alloc((size_t)NBA * 4);
  int* curC  = (int*)alloc((size_t)NBC * 4);
  unsigned* binA = (unsigned*)alloc((size_t)NE * 4);
  unsigned* binC = (unsigned*)alloc((size_t)NE * 4);
  int* rpa   = (int*)alloc((size_t)(NAN_ + 1) * 4);
  int* rpc   = (int*)alloc((size_t)(NCN + 1) * 4);
  int* cola  = (int*)alloc((size_t)NE * 4);
  int* colc  = (int*)alloc((size_t)NE * 4);
  unsigned short* XC = (unsigned short*)alloc((size_t)NCN * DIM * 2);
  unsigned short* XA = (unsigned short*)alloc((size_t)NAN_ * DIM * 2);
  unsigned short* HA = (unsigned short*)alloc((size_t)NAN_ * DIM * 2);  // h_a
  unsigned short* HC = (unsigned short*)alloc((size_t)NCN * DIM * 2);   // h_c
  unsigned short* UA = (unsigned short*)alloc((size_t)NAN_ * DIM * 2);  // decoder U_a
  unsigned short* UC = (unsigned short*)alloc((size_t)NCN * DIM * 2);   // decoder U_c
  unsigned short* Wt    = (unsigned short*)alloc(8 * 16384 * 2);
  unsigned short* Wpt_c = (unsigned short*)alloc(16384 * 2);
  unsigned short* Wpt_a = (unsigned short*)alloc(16384 * 2);
  float* bnbuf = (float*)alloc(512 * 4);
  float* bfull = (float*)alloc(128 * 4);
  // layer-2 outputs alias layer-1 inputs (dead after layer 1; NOT in-place within a launch)
  unsigned short* ZA = XA;
  unsigned short* ZC = XC;

  // --- bf16 pre-cast of node features ---
  k_cast<<<(NCN * DIM / 4 + 255) / 256, 256, 0, stream>>>(x_c, XC, NCN * DIM / 4);
  k_cast<<<(NAN_ * DIM / 4 + 255) / 256, 256, 0, stream>>>(x_a, XA, NAN_ * DIM / 4);

  // --- CSR build via 64-wide destination buckets ---
  (void)hipMemsetAsync(cnt, 0, (size_t)(NBA + NBC) * 4, stream);
  k_bcnt<<<NCHUNK, 256, 0, stream>>>(e_src, e_dst, cntA, cntC);
  k_scan2<<<2, 256, 0, stream>>>(cntA, baseA, curA, cntC, baseC, curC);
  k_bin<<<NCHUNK, 256, 0, stream>>>(e_src, e_dst, curA, curC, binA, binC);
  k_csr<<<NBA, 256, 0, stream>>>(binA, baseA, rpa, cola, NAN_, NBA);
  k_csr<<<NBC, 256, 0, stream>>>(binC, baseC, rpc, colc, NCN, NBC);

  // --- transpose+cast the 8 encoder weights to bf16 [n][k] ---
  WtArgs wa;
  wa.s[0] = Wm1ca; wa.s[1] = Ws1a; wa.s[2] = Wm1ac; wa.s[3] = Ws1c;
  wa.s[4] = Wm2ca; wa.s[5] = Ws2a; wa.s[6] = Wm2ac; wa.s[7] = Ws2c;
  k_wtrans<<<8, 256, 0, stream>>>(wa, Wt);

  int gba = (NAN_ + 127) / 128, gbc = (NCN + 127) / 128;
  (void)hipMemsetAsync(bnbuf, 0, 512 * 4, stream);

  // --- layer 1 (gather-mean fused into GEMM) ---
  k_gemm<<<gba, 256, 0, stream>>>(nullptr, rpa, cola, XC, Wt + 0 * 16384,
                                  XA, Wt + 1 * 16384, b1a, HA, NAN_, 1, nullptr, nullptr);
  k_gemm<<<gbc, 256, 0, stream>>>(nullptr, rpc, colc, XA, Wt + 2 * 16384,
                                  XC, Wt + 3 * 16384, b1c, HC, NCN, 1, nullptr, nullptr);

  // --- layer 2 (fused gather + BN stats in epilogue; outputs to ZA/ZC) ---
  k_gemm<<<gba, 256, 0, stream>>>(nullptr, rpa, cola, HC, Wt + 4 * 16384,
                                  HA, Wt + 5 * 16384, b2a, ZA, NAN_, 0, bnbuf + 0,   bnbuf + 128);
  k_gemm<<<gbc, 256, 0, stream>>>(nullptr, rpc, colc, HA, Wt + 6 * 16384,
                                  HC, Wt + 7 * 16384, b2c, ZC, NCN, 0, bnbuf + 256, bnbuf + 384);

  // --- BN finalize folded into decoder weights ---
  k_bnprep<<<1, 128, 0, stream>>>(bnbuf, bng_c, bnb_c, bng_a, bnb_a, Wd1, bd1,
                                  Wpt_c, Wpt_a, bfull);

  // --- decoder precompute U = zbn @ W_dec1_half (dense GEMM, no gather) ---
  k_gemm<<<gba, 256, 0, stream>>>(ZA, nullptr, nullptr, nullptr, Wpt_a,
                                  nullptr, nullptr, nullptr, UA, NAN_, 0, nullptr, nullptr);
  k_gemm<<<gbc, 256, 0, stream>>>(ZC, nullptr, nullptr, nullptr, Wpt_c,
                                  nullptr, nullptr, nullptr, UC, NCN, 0, nullptr, nullptr);

  // --- per-edge decoder ---
  k_dec<<<4096, 256, 0, stream>>>(l_c, l_a, UC, UA, bfull, Wd2, bd2, out, NL);
}

// Round 5
// 1292.597 us; speedup vs baseline: 1.4441x; 1.4441x over previous
//
#include <hip/hip_runtime.h>
#include <hip/hip_bf16.h>

#define NCN 300000
#define NAN_ 100000
#define DIM 128
#define NE 2000000
#define NL 1000000
#define NBA 1563          // ceil(NAN_/64)
#define NBC 4688          // ceil(NCN/64)
#define ECH 8192          // edges per binning block
#define NCHUNK ((NE + ECH - 1) / ECH)

typedef __attribute__((ext_vector_type(8))) short bf16x8;
typedef __attribute__((ext_vector_type(4))) float f32x4;
typedef __attribute__((ext_vector_type(8))) unsigned short u16x8;
typedef __attribute__((ext_vector_type(4))) unsigned short u16x4;

static __device__ __forceinline__ unsigned short f2bf(float x){
  union { float f; unsigned u; } v; v.f = x;
  unsigned r = (v.u + 0x7FFFu + ((v.u >> 16) & 1u)) >> 16;
  return (unsigned short)r;
}
static __device__ __forceinline__ float bf2f(unsigned short h){
  union { unsigned u; float f; } v; v.u = ((unsigned)h) << 16; return v.f;
}

// ---------------- fp32 -> bf16 cast, both feature arrays in one launch ----------------
__global__ void k_cast2(const float* __restrict__ x0, unsigned short* __restrict__ y0, int n0,
                        const float* __restrict__ x1, unsigned short* __restrict__ y1, int n1){
  int i = blockIdx.x * blockDim.x + threadIdx.x;
  const float* x; unsigned short* y;
  if (i < n0){ x = x0; y = y0; }
  else if (i < n0 + n1){ x = x1; y = y1; i -= n0; }
  else return;
  float4 v = ((const float4*)x)[i];
  u16x4 h;
  h[0] = f2bf(v.x); h[1] = f2bf(v.y); h[2] = f2bf(v.z); h[3] = f2bf(v.w);
  ((u16x4*)y)[i] = h;
}

// ---------- pass 0: per-block LDS histogram of 64-wide dst buckets, both dirs ----------
__global__ void k_bcnt(const int* __restrict__ src, const int* __restrict__ dst,
                       int* cntA, int* cntC){
  __shared__ int h[NBA + NBC];
  int t = threadIdx.x;
  for (int i = t; i < NBA + NBC; i += 256) h[i] = 0;
  __syncthreads();
  int e0 = blockIdx.x * ECH;
  int e1 = e0 + ECH < NE ? e0 + ECH : NE;
  for (int e = e0 + t; e < e1; e += 256){
    int s = src[e], d = dst[e];
    atomicAdd(&h[d >> 6], 1);
    atomicAdd(&h[NBA + (s >> 6)], 1);
  }
  __syncthreads();
  for (int i = t; i < NBA + NBC; i += 256){
    int c = h[i];
    if (c > 0){
      if (i < NBA) atomicAdd(&cntA[i], c);
      else         atomicAdd(&cntC[i - NBA], c);
    }
  }
}

// ---------- scan bucket counts (block 0: A, block 1: C); writes base (excl) + cur copy ----
__global__ void k_scan2(const int* cA, int* bA, int* uA,
                        const int* cC, int* bC, int* uC){
  const int* c; int* bs; int* cu; int n;
  if (blockIdx.x == 0){ c = cA; bs = bA; cu = uA; n = NBA; }
  else                { c = cC; bs = bC; cu = uC; n = NBC; }
  int t = threadIdx.x;
  int per = (n + 255) / 256;          // <= 19
  int b0 = t * per;
  int vals[19];
  int s = 0;
  for (int i = 0; i < per; i++){
    int idx = b0 + i;
    int x = (idx < n) ? c[idx] : 0;
    vals[i] = s; s += x;
  }
  int lane = t & 63, w = t >> 6;
  int inc = s;
  #pragma unroll
  for (int o = 1; o < 64; o <<= 1){ int u = __shfl_up(inc, o); if (lane >= o) inc += u; }
  __shared__ int ws[4];
  if (lane == 63) ws[w] = inc;
  __syncthreads();
  int woff = 0;
  for (int j = 0; j < w; j++) woff += ws[j];
  int ex = woff + inc - s;
  for (int i = 0; i < per; i++){
    int idx = b0 + i;
    if (idx < n){ int v = ex + vals[i]; bs[idx] = v; cu[idx] = v; }
  }
  if (t == 255) bs[n] = ex + s;       // == NE
}

// ---------- pass 1: partition edges into packed (dstlow<<26|src) per bucket ----------
__global__ void k_bin(const int* __restrict__ src, const int* __restrict__ dst,
                      int* curA, int* curC, unsigned* binA, unsigned* binC){
  __shared__ int h[NBA + NBC];
  int t = threadIdx.x;
  for (int i = t; i < NBA + NBC; i += 256) h[i] = 0;
  __syncthreads();
  int e0 = blockIdx.x * ECH;
  int e1 = e0 + ECH < NE ? e0 + ECH : NE;
  for (int e = e0 + t; e < e1; e += 256){
    int s = src[e], d = dst[e];
    atomicAdd(&h[d >> 6], 1);
    atomicAdd(&h[NBA + (s >> 6)], 1);
  }
  __syncthreads();
  for (int i = t; i < NBA + NBC; i += 256){
    int c = h[i];
    if (c > 0){
      int base = (i < NBA) ? atomicAdd(&curA[i], c) : atomicAdd(&curC[i - NBA], c);
      h[i] = base;
    }
  }
  __syncthreads();
  for (int e = e0 + t; e < e1; e += 256){
    int s = src[e], d = dst[e];
    int pa = atomicAdd(&h[d >> 6], 1);
    binA[pa] = ((unsigned)(d & 63) << 26) | (unsigned)s;
    int pc = atomicAdd(&h[NBA + (s >> 6)], 1);
    binC[pc] = ((unsigned)(s & 63) << 26) | (unsigned)d;
  }
}

// ---------- pass 2: per-bucket CSR finalize — both directions in one launch ----------
__global__ void k_csrm(const unsigned* __restrict__ binA, const int* __restrict__ baseA,
                       int* __restrict__ rpa, int* __restrict__ cola,
                       const unsigned* __restrict__ binC, const int* __restrict__ baseC,
                       int* __restrict__ rpc, int* __restrict__ colc){
  int b = blockIdx.x;
  const unsigned* bin; const int* base; int* rp; int* col; int ndst, nb, bb;
  if (b < NBA){ bin = binA; base = baseA; rp = rpa; col = cola; ndst = NAN_; nb = NBA; bb = b; }
  else        { bin = binC; base = baseC; rp = rpc; col = colc; ndst = NCN; nb = NBC; bb = b - NBA; }
  int beg = base[bb], end = base[bb + 1];
  __shared__ int deg[64], cur[64];
  int t = threadIdx.x;
  if (t < 64) deg[t] = 0;
  __syncthreads();
  for (int i = beg + t; i < end; i += 256){
    unsigned p = bin[i];
    atomicAdd(&deg[p >> 26], 1);
  }
  __syncthreads();
  if (t < 64){
    int v = deg[t];
    int inc = v;
    #pragma unroll
    for (int o = 1; o < 64; o <<= 1){ int u = __shfl_up(inc, o); if (t >= o) inc += u; }
    int ex = beg + inc - v;
    cur[t] = ex;
    int d0 = bb << 6;
    if (d0 + t < ndst) rp[d0 + t] = ex;
    if (bb == nb - 1 && t == 0) rp[ndst] = base[nb];
  }
  __syncthreads();
  for (int i = beg + t; i < end; i += 256){
    unsigned p = bin[i];
    int pos = atomicAdd(&cur[p >> 26], 1);
    col[pos] = (int)(p & 0x03FFFFFFu);
  }
}

// ---- pull mean aggregation, both node types: one 16-lane subgroup per destination ----
// 4 destinations per wave; per-subgroup edge loop unrolled x4 -> ~16 gathers in flight
// per wave, zero cross-lane shuffles.
__global__ void k_agg2(const unsigned short* __restrict__ fA, const int* __restrict__ rpA,
                       const int* __restrict__ colA, unsigned short* __restrict__ oA,
                       const unsigned short* __restrict__ fC, const int* __restrict__ rpC,
                       const int* __restrict__ colC, unsigned short* __restrict__ oC){
  int qid = (blockIdx.x * blockDim.x + threadIdx.x) >> 4;
  int cl  = threadIdx.x & 15;          // 8-channel chunk index
  const unsigned short* feat; const int* rp; const int* col; unsigned short* outm; int d;
  if (qid < NAN_){ feat = fA; rp = rpA; col = colA; outm = oA; d = qid; }
  else if (qid < NAN_ + NCN){ feat = fC; rp = rpC; col = colC; outm = oC; d = qid - NAN_; }
  else return;
  int beg = rp[d], end = rp[d + 1];
  float acc[8] = {0.f,0.f,0.f,0.f,0.f,0.f,0.f,0.f};
  int j = beg;
  for (; j + 3 < end; j += 4){
    int4 cs = *(const int4*)(col + j);           // broadcast within subgroup
    u16x8 v0 = *(const u16x8*)(feat + (size_t)cs.x * DIM + cl * 8);
    u16x8 v1 = *(const u16x8*)(feat + (size_t)cs.y * DIM + cl * 8);
    u16x8 v2 = *(const u16x8*)(feat + (size_t)cs.z * DIM + cl * 8);
    u16x8 v3 = *(const u16x8*)(feat + (size_t)cs.w * DIM + cl * 8);
    #pragma unroll
    for (int k = 0; k < 8; k++)
      acc[k] += (bf2f(v0[k]) + bf2f(v1[k])) + (bf2f(v2[k]) + bf2f(v3[k]));
  }
  for (; j < end; ++j){
    int s = col[j];
    u16x8 v = *(const u16x8*)(feat + (size_t)s * DIM + cl * 8);
    #pragma unroll
    for (int k = 0; k < 8; k++) acc[k] += bf2f(v[k]);
  }
  int dg = end - beg;
  float inv = 1.0f / (float)(dg > 1 ? dg : 1);
  u16x8 r;
  #pragma unroll
  for (int k = 0; k < 8; k++) r[k] = f2bf(acc[k] * inv);
  *(u16x8*)(outm + (size_t)d * DIM + cl * 8) = r;
}

// ------- bf16 MFMA GEMM, two independent jobs per launch (grid split) -------
struct GJob {
  const unsigned short* A; const unsigned short* WtA;
  const unsigned short* B; const unsigned short* WtB;
  const float* bias; unsigned short* out; int M; int doRelu;
  float* gsum; float* gsq;
};

__global__ __launch_bounds__(256) void k_gemm2(GJob j0, GJob j1, int split){
  GJob jb;
  int bid;
  if ((int)blockIdx.x < split){ jb = j0; bid = blockIdx.x; }
  else                        { jb = j1; bid = blockIdx.x - split; }
  __shared__ unsigned short lA[128 * 128];   // 32 KB, xor-swizzled 16B chunks
  __shared__ unsigned short lW[128 * 128];   // 32 KB
  int t = threadIdx.x;
  int lane = t & 63, wv = t >> 6;
  int row0 = bid * 128;
  int m = lane & 15, kq = lane >> 4;
  int M = jb.M;

  f32x4 acc[2][8];
  #pragma unroll
  for (int i = 0; i < 2; i++)
    #pragma unroll
    for (int j = 0; j < 8; j++) acc[i][j] = (f32x4){0.f, 0.f, 0.f, 0.f};

  const unsigned short* src = jb.A;
  const unsigned short* wt = jb.WtA;
  for (int pass = 0; pass < 2; ++pass){
    if (pass == 1){
      if (!jb.B) break;
      src = jb.B; wt = jb.WtB;
      __syncthreads();
    }
    #pragma unroll
    for (int i = 0; i < 8; i++){
      int id = t + 256 * i;
      int r = id >> 4, c = id & 15;
      int gr = row0 + r;
      u16x8 v = {0,0,0,0,0,0,0,0};
      if (gr < M) v = *(const u16x8*)(src + (size_t)gr * DIM + c * 8);
      int pc = c ^ (r & 15);
      *(u16x8*)&lA[r * 128 + pc * 8] = v;
    }
    #pragma unroll
    for (int i = 0; i < 8; i++){
      int id = t + 256 * i;
      int n = id >> 4, cc = id & 15;
      u16x8 w = *(const u16x8*)(wt + n * 128 + cc * 8);
      int pc = cc ^ (n & 15);
      *(u16x8*)&lW[n * 128 + pc * 8] = w;
    }
    __syncthreads();
    #pragma unroll
    for (int kc = 0; kc < 4; kc++){
      int cA = kc * 4 + kq;
      int r0 = wv * 32 + m;
      int r1 = r0 + 16;
      bf16x8 a0 = *(const bf16x8*)&lA[r0 * 128 + (cA ^ m) * 8];
      bf16x8 a1 = *(const bf16x8*)&lA[r1 * 128 + (cA ^ m) * 8];
      #pragma unroll
      for (int ct = 0; ct < 8; ct++){
        int n = ct * 16 + m;
        bf16x8 bfrag = *(const bf16x8*)&lW[n * 128 + (cA ^ m) * 8];
        acc[0][ct] = __builtin_amdgcn_mfma_f32_16x16x32_bf16(a0, bfrag, acc[0][ct], 0, 0, 0);
        acc[1][ct] = __builtin_amdgcn_mfma_f32_16x16x32_bf16(a1, bfrag, acc[1][ct], 0, 0, 0);
      }
    }
  }
  // epilogue: D col = lane&15, row = (lane>>4)*4 + reg   [verified m89/m91]
  float* lsum = (float*)lA;   // LDS reuse after barrier
  float* lsq  = lsum + 128;
  if (jb.gsum){
    __syncthreads();
    if (t < 128){ lsum[t] = 0.f; lsq[t] = 0.f; }
    __syncthreads();
  }
  #pragma unroll
  for (int ct = 0; ct < 8; ct++){
    int colv = ct * 16 + m;
    float bv = jb.bias ? jb.bias[colv] : 0.f;
    float ps = 0.f, pq = 0.f;
    #pragma unroll
    for (int rt = 0; rt < 2; rt++){
      int rbase = row0 + wv * 32 + rt * 16 + kq * 4;
      #pragma unroll
      for (int r = 0; r < 4; r++){
        int grow = rbase + r;
        if (grow < M){
          float vo = acc[rt][ct][r] + bv;
          if (jb.doRelu) vo = fmaxf(vo, 0.f);
          jb.out[(size_t)grow * DIM + colv] = f2bf(vo);
          ps += vo; pq += vo * vo;
        }
      }
    }
    if (jb.gsum){
      atomicAdd(&lsum[colv], ps);
      atomicAdd(&lsq[colv], pq);
    }
  }
  if (jb.gsum){
    __syncthreads();
    if (t < 128){
      atomicAdd(&jb.gsum[t], lsum[t]);
      atomicAdd(&jb.gsq[t],  lsq[t]);
    }
  }
}

// ---------------- weight transpose fp32 [k][n] -> bf16 [n][k], batched ----------------
struct WtArgs { const float* s[8]; };
__global__ void k_wtrans(WtArgs a, unsigned short* dstb){
  const float* W = a.s[blockIdx.x];
  unsigned short* Wt = dstb + blockIdx.x * 16384;
  int t = threadIdx.x;
  for (int i = 0; i < 64; i++){
    int id = t + 256 * i;
    int k = id >> 7, n = id & 127;
    Wt[n * 128 + k] = f2bf(W[id]);
  }
}

// bn finalize + fold BN into decoder weight halves; bfull = b_dec1 + t_c@Wc + t_a@Wa
__global__ void k_bnprep(const float* sums,   // [sum_a, sq_a, sum_c, sq_c] x128
                         const float* gc, const float* bc,
                         const float* ga, const float* ba,
                         const float* Wd1, const float* bd1,
                         unsigned short* Wpt_c, unsigned short* Wpt_a, float* bfull){
  int n = threadIdx.x;   // 128 threads
  __shared__ float sc[128], tc[128], sa[128], ta[128];
  {
    float mu = sums[256 + n] / (float)NCN;
    float var = sums[384 + n] / (float)NCN - mu * mu;
    float s = gc[n] * rsqrtf(var + 1e-5f);
    sc[n] = s; tc[n] = bc[n] - mu * s;
  }
  {
    float mu = sums[0 + n] / (float)NAN_;
    float var = sums[128 + n] / (float)NAN_ - mu * mu;
    float s = ga[n] * rsqrtf(var + 1e-5f);
    sa[n] = s; ta[n] = ba[n] - mu * s;
  }
  __syncthreads();
  float accv = bd1[n];
  for (int k = 0; k < 128; k++){
    float w1 = Wd1[k * DIM + n];
    float w2 = Wd1[(128 + k) * DIM + n];
    Wpt_c[n * 128 + k] = f2bf(sc[k] * w1);
    Wpt_a[n * 128 + k] = f2bf(sa[k] * w2);
    accv += tc[k] * w1 + ta[k] * w2;
  }
  bfull[n] = accv;
}

// ---------------- decoder: quarter-wave per edge, 2 edges in flight ----------------
__global__ void k_dec(const int* __restrict__ lc, const int* __restrict__ la,
                      const unsigned short* __restrict__ UC, const unsigned short* __restrict__ UA,
                      const float* __restrict__ bfull, const float* __restrict__ w2,
                      const float* __restrict__ b2, float* __restrict__ out, int Etot){
  int t  = blockIdx.x * blockDim.x + threadIdx.x;
  int sl = t & 15;
  int q  = t >> 4;
  int nq = (gridDim.x * blockDim.x) >> 4;
  float bb[8], ww[8];
  #pragma unroll
  for (int k = 0; k < 8; k++){ bb[k] = bfull[sl * 8 + k]; ww[k] = w2[sl * 8 + k]; }
  float b2v = b2[0];
  for (int e0 = q * 2; e0 < Etot; e0 += nq * 2){
    int e1 = e0 + 1;                  // Etot even -> always valid
    int ic0 = lc[e0], ia0 = la[e0];
    int ic1 = lc[e1], ia1 = la[e1];
    u16x8 uc0 = *(const u16x8*)(UC + (size_t)ic0 * DIM + sl * 8);
    u16x8 ua0 = *(const u16x8*)(UA + (size_t)ia0 * DIM + sl * 8);
    u16x8 uc1 = *(const u16x8*)(UC + (size_t)ic1 * DIM + sl * 8);
    u16x8 ua1 = *(const u16x8*)(UA + (size_t)ia1 * DIM + sl * 8);
    float d0 = 0.f, d1 = 0.f;
    #pragma unroll
    for (int k = 0; k < 8; k++){
      float x0 = fmaxf(bf2f(uc0[k]) + bf2f(ua0[k]) + bb[k], 0.f);
      float x1 = fmaxf(bf2f(uc1[k]) + bf2f(ua1[k]) + bb[k], 0.f);
      d0 += x0 * ww[k];
      d1 += x1 * ww[k];
    }
    #pragma unroll
    for (int o = 8; o; o >>= 1){ d0 += __shfl_xor(d0, o); d1 += __shfl_xor(d1, o); }
    if (sl == 0){ out[e0] = d0 + b2v; out[e1] = d1 + b2v; }
  }
}

extern "C" void kernel_launch(void* const* d_in, const int* in_sizes, int n_in,
                              void* d_out, int out_size, void* d_ws, size_t ws_size,
                              hipStream_t stream){
  const float* x_c  = (const float*)d_in[0];
  const float* x_a  = (const float*)d_in[1];
  const int* e_src  = (const int*)d_in[2];
  const int* e_dst  = (const int*)d_in[3];
  const int* l_c    = (const int*)d_in[4];
  const int* l_a    = (const int*)d_in[5];
  const float* Wm1ca = (const float*)d_in[6];
  const float* Ws1a  = (const float*)d_in[7];
  const float* b1a   = (const float*)d_in[8];
  const float* Wm1ac = (const float*)d_in[9];
  const float* Ws1c  = (const float*)d_in[10];
  const float* b1c   = (const float*)d_in[11];
  const float* Wm2ca = (const float*)d_in[12];
  const float* Ws2a  = (const float*)d_in[13];
  const float* b2a   = (const float*)d_in[14];
  const float* Wm2ac = (const float*)d_in[15];
  const float* Ws2c  = (const float*)d_in[16];
  const float* b2c   = (const float*)d_in[17];
  const float* bng_c = (const float*)d_in[18];
  const float* bnb_c = (const float*)d_in[19];
  const float* bng_a = (const float*)d_in[20];
  const float* bnb_a = (const float*)d_in[21];
  const float* Wd1   = (const float*)d_in[22];
  const float* bd1   = (const float*)d_in[23];
  const float* Wd2   = (const float*)d_in[24];
  const float* bd2   = (const float*)d_in[25];
  float* out = (float*)d_out;

  // workspace carve (~340 MB)
  char* p = (char*)d_ws;
  auto alloc = [&](size_t bytes) -> char* {
    char* r = p; p += (bytes + 255) & ~(size_t)255; return r;
  };
  int* cnt   = (int*)alloc((size_t)(NBA + NBC) * 4);
  int* cntA  = cnt;
  int* cntC  = cnt + NBA;
  int* baseA = (int*)alloc((size_t)(NBA + 1) * 4);
  int* baseC = (int*)alloc((size_t)(NBC + 1) * 4);
  int* curA  = (int*)alloc((size_t)NBA * 4);
  int* curC  = (int*)alloc((size_t)NBC * 4);
  unsigned* binA = (unsigned*)alloc((size_t)NE * 4);
  unsigned* binC = (unsigned*)alloc((size_t)NE * 4);
  int* rpa   = (int*)alloc((size_t)(NAN_ + 1) * 4);
  int* rpc   = (int*)alloc((size_t)(NCN + 1) * 4);
  int* cola  = (int*)alloc((size_t)NE * 4);
  int* colc  = (int*)alloc((size_t)NE * 4);
  unsigned short* XC = (unsigned short*)alloc((size_t)NCN * DIM * 2);
  unsigned short* XA = (unsigned short*)alloc((size_t)NAN_ * DIM * 2);
  unsigned short* MA = (unsigned short*)alloc((size_t)NAN_ * DIM * 2);  // mean_a -> U_a
  unsigned short* MC = (unsigned short*)alloc((size_t)NCN * DIM * 2);   // mean_c -> U_c
  unsigned short* HA = (unsigned short*)alloc((size_t)NAN_ * DIM * 2);  // h_a
  unsigned short* HC = (unsigned short*)alloc((size_t)NCN * DIM * 2);   // h_c
  unsigned short* Wt    = (unsigned short*)alloc(8 * 16384 * 2);
  unsigned short* Wpt_c = (unsigned short*)alloc(16384 * 2);
  unsigned short* Wpt_a = (unsigned short*)alloc(16384 * 2);
  float* bnbuf = (float*)alloc(512 * 4);
  float* bfull = (float*)alloc(128 * 4);
  // layer-2 outputs alias layer-1 inputs (dead after layer-1 GEMMs)
  unsigned short* ZA = XA;
  unsigned short* ZC = XC;

  // --- bf16 pre-cast of node features (one launch) ---
  int nc4 = NCN * DIM / 4, na4 = NAN_ * DIM / 4;
  k_cast2<<<(nc4 + na4 + 255) / 256, 256, 0, stream>>>(x_c, XC, nc4, x_a, XA, na4);

  // --- CSR build via 64-wide destination buckets ---
  (void)hipMemsetAsync(cnt, 0, (size_t)(NBA + NBC) * 4, stream);
  k_bcnt<<<NCHUNK, 256, 0, stream>>>(e_src, e_dst, cntA, cntC);
  k_scan2<<<2, 256, 0, stream>>>(cntA, baseA, curA, cntC, baseC, curC);
  k_bin<<<NCHUNK, 256, 0, stream>>>(e_src, e_dst, curA, curC, binA, binC);
  k_csrm<<<NBA + NBC, 256, 0, stream>>>(binA, baseA, rpa, cola, binC, baseC, rpc, colc);

  // --- transpose+cast the 8 encoder weights to bf16 [n][k] ---
  WtArgs wa;
  wa.s[0] = Wm1ca; wa.s[1] = Ws1a; wa.s[2] = Wm1ac; wa.s[3] = Ws1c;
  wa.s[4] = Wm2ca; wa.s[5] = Ws2a; wa.s[6] = Wm2ac; wa.s[7] = Ws2c;
  k_wtrans<<<8, 256, 0, stream>>>(wa, Wt);

  int agg_blocks = ((NAN_ + NCN) * 16 + 255) / 256;
  int gba = (NAN_ + 127) / 128, gbc = (NCN + 127) / 128;
  (void)hipMemsetAsync(bnbuf, 0, 512 * 4, stream);

  // --- layer 1 ---
  k_agg2<<<agg_blocks, 256, 0, stream>>>(XC, rpa, cola, MA, XA, rpc, colc, MC);
  {
    GJob ja = { MA, Wt + 0 * 16384, XA, Wt + 1 * 16384, b1a, HA, NAN_, 1, nullptr, nullptr };
    GJob jc = { MC, Wt + 2 * 16384, XC, Wt + 3 * 16384, b1c, HC, NCN, 1, nullptr, nullptr };
    k_gemm2<<<gba + gbc, 256, 0, stream>>>(ja, jc, gba);
  }

  // --- layer 2 (BN column stats fused into epilogue; outputs to ZA/ZC) ---
  k_agg2<<<agg_blocks, 256, 0, stream>>>(HC, rpa, cola, MA, HA, rpc, colc, MC);
  {
    GJob ja = { MA, Wt + 4 * 16384, HA, Wt + 5 * 16384, b2a, ZA, NAN_, 0, bnbuf + 0,   bnbuf + 128 };
    GJob jc = { MC, Wt + 6 * 16384, HC, Wt + 7 * 16384, b2c, ZC, NCN, 0, bnbuf + 256, bnbuf + 384 };
    k_gemm2<<<gba + gbc, 256, 0, stream>>>(ja, jc, gba);
  }

  // --- BN finalize folded into decoder weights ---
  k_bnprep<<<1, 128, 0, stream>>>(bnbuf, bng_c, bnb_c, bng_a, bnb_a, Wd1, bd1,
                                  Wpt_c, Wpt_a, bfull);

  // --- decoder precompute U = zbn @ W_dec1_half (U reuses MA/MC) ---
  {
    GJob ja = { ZA, Wpt_a, nullptr, nullptr, nullptr, MA, NAN_, 0, nullptr, nullptr };
    GJob jc = { ZC, Wpt_c, nullptr, nullptr, nullptr, MC, NCN, 0, nullptr, nullptr };
    k_gemm2<<<gba + gbc, 256, 0, stream>>>(ja, jc, gba);
  }

  // --- per-edge decoder ---
  k_dec<<<4096, 256, 0, stream>>>(l_c, l_a, MC, MA, bfull, Wd2, bd2, out, NL);
}